// Round 7
// baseline (2009.692 us; speedup 1.0000x reference)
//
#include <hip/hip_runtime.h>
#include <hip/hip_bf16.h>
#include <math.h>

// Problem constants
#define NTOT 4096      // B*N nodes
#define NEDGE 65536    // E edges
#define BSZ 64         // batch
#define NN 64          // nodes per trajectory
#define HDIM 1024      // LSTM hidden
#define TIN 10
#define TOUT 6
#define FRAME_ELEMS (NTOT * 2)   // 8192 floats per frame

typedef short s16x8 __attribute__((ext_vector_type(8)));
typedef float f32x4 __attribute__((ext_vector_type(4)));

__device__ __forceinline__ unsigned short f2bf(float f) {
    union { float f; unsigned u; } x; x.f = f;
    unsigned r = x.u + 0x7fffu + ((x.u >> 16) & 1u);
    return (unsigned short)(r >> 16);
}

// ==================== combined weight transpose (task list) ====================
struct TT { const float* W; float* WT; int NO; int K; int toff; };
struct TT8 { TT t[8]; };

__global__ __launch_bounds__(256) void transpose_all(TT8 tasks) {
    int bid = blockIdx.x;
    int ti = 0;
    #pragma unroll
    for (int j = 1; j < 8; ++j) if (bid >= tasks.t[j].toff) ti = j;
    TT tk = tasks.t[ti];
    int local = bid - tk.toff;
    int tilesK = tk.K >> 5;
    int kb = local % tilesK, nb = local / tilesK;
    int k0 = kb * 32, n0 = nb * 32;
    __shared__ float t[32][33];
    int tx = threadIdx.x & 31, ty = threadIdx.x >> 5;  // 32 x 8
    #pragma unroll
    for (int i = 0; i < 4; ++i)
        t[ty + i * 8][tx] = tk.W[(size_t)(n0 + ty + i * 8) * tk.K + k0 + tx];
    __syncthreads();
    #pragma unroll
    for (int i = 0; i < 4; ++i)
        tk.WT[(size_t)(k0 + ty + i * 8) * tk.NO + n0 + tx] = t[tx][ty + i * 8];
}

// ==================== batched GCN over 10 input frames ====================

__global__ void bgcn_init_xw(const float* __restrict__ feat, const float* __restrict__ wg,
                             float* __restrict__ deg, float* __restrict__ xw) {
    int i = blockIdx.x * blockDim.x + threadIdx.x;
    if (i >= 10 * NTOT) return;
    deg[i] = 1.0f;
    float x0 = feat[i * 2], x1 = feat[i * 2 + 1];
    xw[i * 2]     = x0 * wg[0] + x1 * wg[1];
    xw[i * 2 + 1] = x0 * wg[2] + x1 * wg[3];
}

__global__ void bgcn_count(const int* __restrict__ ei, float* __restrict__ deg) {
    int e = blockIdx.x * blockDim.x + threadIdx.x;
    if (e >= 10 * NEDGE) return;
    int t = e >> 16, el = e & 65535;
    int dst = ei[t * 2 * NEDGE + NEDGE + el];
    atomicAdd(&deg[t * NTOT + dst], 1.0f);
}

__global__ void bgcn_node(const float* __restrict__ bg, float* __restrict__ deg,
                          const float* __restrict__ xw, float* __restrict__ gT_all) {
    int i = blockIdx.x * blockDim.x + threadIdx.x;
    if (i >= 10 * NTOT) return;
    float dinv = rsqrtf(deg[i]);
    deg[i] = dinv;
    int t = i >> 12, node = i & 4095;
    int b = node >> 6, nn = node & 63;
    float w2 = dinv * dinv;
    gT_all[t * 8192 + (nn * 2 + 0) * 64 + b] = xw[i * 2]     * w2 + bg[0];
    gT_all[t * 8192 + (nn * 2 + 1) * 64 + b] = xw[i * 2 + 1] * w2 + bg[1];
}

// LDS-accumulated edge scatter: 8 blocks per frame
__global__ __launch_bounds__(256) void bgcn_scatter_lds(const int* __restrict__ ei,
                                                        const float* __restrict__ dinv,
                                                        const float* __restrict__ xw,
                                                        float* __restrict__ gT_all) {
    __shared__ float sg[8192];
    int t = blockIdx.x >> 3;
    int chunk = blockIdx.x & 7;
    for (int i = threadIdx.x; i < 8192; i += 256) sg[i] = 0.f;
    __syncthreads();
    const int* eis = ei + t * 2 * NEDGE;
    int e0 = chunk * 8192;
    for (int e = e0 + threadIdx.x; e < e0 + 8192; e += 256) {
        int s = eis[e];
        int d = eis[NEDGE + e];
        float w = dinv[t * NTOT + s] * dinv[t * NTOT + d];
        int b = d >> 6, nn = d & 63;
        atomicAdd(&sg[(nn * 2 + 0) * 64 + b], xw[(t * NTOT + s) * 2]     * w);
        atomicAdd(&sg[(nn * 2 + 1) * 64 + b], xw[(t * NTOT + s) * 2 + 1] * w);
    }
    __syncthreads();
    float* gt = gT_all + t * 8192;
    for (int i = threadIdx.x; i < 8192; i += 256) {
        float v = sg[i];
        if (v != 0.f) atomicAdd(&gt[i], v);
    }
}

// ==================== broadcast-x GEMM v4: 128n x 64m tile, 4n x 8m per thread ====================
// P[ks][n][m] = sum over k-chunk ks of in[m][k] * W[n][k].
// thread: ns = tid>>3 (0..31) -> n = ns*4 (4 consecutive n, float4 W loads);
//         q = tid&7 -> m in [q*8, q*8+8).
template<int KC>
__global__ __launch_bounds__(256) void gemm_bx4(
    const float* __restrict__ inT, const float* __restrict__ inT2,
    const float* __restrict__ WT,  const float* __restrict__ WT2,
    float* __restrict__ P, int NO, int SK1)
{
    constexpr int STG = (KC > 128) ? 128 : KC;
    __shared__ float xs[STG * 64];
    int tid = threadIdx.x, ks = blockIdx.y;
    const float* xsrc; const float* wsrc;
    if (ks < SK1) { xsrc = inT  + (size_t)ks * KC * 64;         wsrc = WT  + (size_t)ks * KC * NO; }
    else          { xsrc = inT2 + (size_t)(ks - SK1) * KC * 64; wsrc = WT2 + (size_t)(ks - SK1) * KC * NO; }
    int ns = tid >> 3, q = tid & 7;
    int n = blockIdx.x * 128 + ns * 4;
    const float* xq = xs + q * 8;
    float acc[4][8];
    #pragma unroll
    for (int j = 0; j < 4; ++j)
        #pragma unroll
        for (int i = 0; i < 8; ++i) acc[j][i] = 0.f;

    for (int kb = 0; kb < KC; kb += STG) {
        if (kb) __syncthreads();
        for (int i = tid; i < STG * 16; i += 256)
            ((float4*)xs)[i] = ((const float4*)(xsrc + (size_t)kb * 64))[i];
        __syncthreads();
        const float* wp = wsrc + (size_t)kb * NO + n;
        float4 wv = *(const float4*)wp;
        for (int k = 0; k < STG; ++k) {
            float4 wnx;
            if (k + 1 < STG) wnx = *(const float4*)(wp + (size_t)(k + 1) * NO);
            float4 xa = *(const float4*)(xq + k * 64);
            float4 xb = *(const float4*)(xq + k * 64 + 4);
            float xr[8] = {xa.x, xa.y, xa.z, xa.w, xb.x, xb.y, xb.z, xb.w};
            float wj[4] = {wv.x, wv.y, wv.z, wv.w};
            #pragma unroll
            for (int j = 0; j < 4; ++j)
                #pragma unroll
                for (int i = 0; i < 8; ++i)
                    acc[j][i] = fmaf(wj[j], xr[i], acc[j][i]);
            wv = wnx;
        }
    }
    #pragma unroll
    for (int j = 0; j < 4; ++j) {
        float* pp = P + ((size_t)ks * NO + n + j) * 64 + q * 8;
        *(float4*)(pp + 0) = make_float4(acc[j][0], acc[j][1], acc[j][2], acc[j][3]);
        *(float4*)(pp + 4) = make_float4(acc[j][4], acc[j][5], acc[j][6], acc[j][7]);
    }
}

// ==================== reduce partials + bias (+relu) -> aT (NO,64) ====================
__global__ void reduce_relu_kernel(const float* __restrict__ P,
                                   const float* __restrict__ bias,
                                   float* __restrict__ aT,
                                   int NO, int SK, int relu) {
    int idx = blockIdx.x * blockDim.x + threadIdx.x;
    if (idx >= NO * 64) return;
    int n = idx >> 6;
    float v = bias[n];
    for (int ks = 0; ks < SK; ++ks) v += P[(size_t)ks * NO * 64 + idx];
    if (relu) v = fmaxf(v, 0.f);
    aT[idx] = v;
}

// ==================== LSTM pointwise from 9 partials (+ optional bf16 h-stash) ====================
__global__ void lstm_update2(const float* __restrict__ P,
                             const float* __restrict__ b_ih, const float* __restrict__ b_hh,
                             float* __restrict__ hT, float* __restrict__ cT,
                             unsigned short* __restrict__ stash, int mbase) {
    int t = blockIdx.x * blockDim.x + threadIdx.x;
    if (t >= HDIM * BSZ) return;
    int j = t >> 6, b = t & 63;
    float g4[4];
    #pragma unroll
    for (int gi = 0; gi < 4; ++gi) {
        int row = gi * HDIM + j;
        float v = b_ih[row] + b_hh[row];
        size_t base = (size_t)row * 64 + b;
        #pragma unroll
        for (int ks = 0; ks < 9; ++ks) v += P[(size_t)ks * 4096 * 64 + base];
        g4[gi] = v;
    }
    float si = 1.f / (1.f + expf(-g4[0]));
    float sf = 1.f / (1.f + expf(-g4[1]));
    float gg = tanhf(g4[2]);
    float so = 1.f / (1.f + expf(-g4[3]));
    float cn = sf * cT[t] + si * gg;
    cT[t] = cn;
    float h = so * tanhf(cn);
    hT[t] = h;
    if (stash) stash[(size_t)(mbase + b) * HDIM + j] = f2bf(h);
}

// ==================== finalize3: reduce l5 partials + l6 GEMM + frame (+adj + dense GCN) ====================
// P: l5 partials (16, 512, 64). wt5: (512,128) = l6 W^T. block = trajectory, 128 threads.
__global__ void finalize3(const float* __restrict__ P, const float* __restrict__ b5,
                          const float* __restrict__ wt5, const float* __restrict__ b6,
                          const float* __restrict__ stats, const float* __restrict__ wg,
                          const float* __restrict__ bg,
                          float* __restrict__ frame, float* __restrict__ gT, int dec)
{
    int b = blockIdx.x;
    int n = threadIdx.x;   // 0..127
    __shared__ float a5[512];
    __shared__ float p[128];
    __shared__ float f0[NN], f1[NN], sxw0[NN], sxw1[NN], sdinv[NN];
    __shared__ int ex[NN];
    #pragma unroll
    for (int j = 0; j < 4; ++j) {
        int k = n * 4 + j;
        float v = b5[k];
        #pragma unroll 4
        for (int ks = 0; ks < 16; ++ks) v += P[((size_t)ks * 512 + k) * 64 + b];
        a5[k] = fmaxf(v, 0.f);
    }
    __syncthreads();
    float acc = b6[n];
    for (int k = 0; k < 512; ++k) acc = fmaf(a5[k], wt5[k * 128 + n], acc);
    p[n] = acc;
    frame[b * 128 + n] = acc;
    if (!dec) return;
    __syncthreads();
    int i = n;
    if (i < NN) {
        float p0 = p[i * 2], p1 = p[i * 2 + 1];
        float d0 = p0 * stats[0] + stats[2];
        float d1 = p1 * stats[1] + stats[3];
        f0[i] = d0; f1[i] = d1;
        ex[i] = (d0 > 0.04f) && (d1 > 0.04f);
        sxw0[i] = p0 * wg[0] + p1 * wg[1];
        sxw1[i] = p0 * wg[2] + p1 * wg[3];
    }
    __syncthreads();
    if (i < NN) {
        float fi0 = f0[i], fi1 = f1[i];
        int exi = ex[i];
        float deg = 0.f;
        for (int j = 0; j < NN; ++j) {
            float dx = fi0 - f0[j], dy = fi1 - f1[j];
            float a = (i == j) ? 1.0f :
                      ((dx * dx + dy * dy <= 100.0f && exi && ex[j]) ? 1.0f : 0.0f);
            deg += a;
        }
        sdinv[i] = rsqrtf(deg);
    }
    __syncthreads();
    if (i < NN) {
        float fi0 = f0[i], fi1 = f1[i];
        int exi = ex[i];
        float a0 = 0.f, a1 = 0.f;
        for (int j = 0; j < NN; ++j) {
            float dx = fi0 - f0[j], dy = fi1 - f1[j];
            float a = (i == j) ? 1.0f :
                      ((dx * dx + dy * dy <= 100.0f && exi && ex[j]) ? 1.0f : 0.0f);
            float an = a * sdinv[j];
            a0 += an * sxw0[j];
            a1 += an * sxw1[j];
        }
        float di = sdinv[i];
        gT[(i * 2 + 0) * 64 + b] = a0 * di + bg[0];
        gT[(i * 2 + 1) * 64 + b] = a1 * di + bg[1];
    }
}

// ==================== combined bf16 pack (task list) ====================
struct PTasks {
    const float* W[6]; unsigned short* Bp[6]; int K[6]; int goff[7];
};
__global__ void pack_all(PTasks pt) {
    int g = blockIdx.x * blockDim.x + threadIdx.x;
    if (g >= pt.goff[6]) return;
    int l = 0;
    #pragma unroll
    for (int j = 1; j < 6; ++j) if (g >= pt.goff[j]) l = j;
    int local = g - pt.goff[l];
    int kgs = pt.K[l] >> 3;
    int kg = local % kgs;
    int n  = local / kgs;
    const float* src = pt.W[l] + (size_t)n * pt.K[l] + (size_t)kg * 8;
    unsigned short* dst = pt.Bp[l] + ((size_t)kg * (pt.goff[l + 1] - pt.goff[l]) / kgs + n) * 8;
    #pragma unroll
    for (int j = 0; j < 8; ++j) dst[j] = f2bf(src[j]);
}

// ==================== batched MFMA MLP layer v2 (register prefetch pipeline) ====================
__global__ __launch_bounds__(256) void gemm_mfma2(
    const unsigned short* __restrict__ inb,
    const unsigned short* __restrict__ Bp,
    const float* __restrict__ bias,
    unsigned short* __restrict__ outb,
    float* __restrict__ frames,
    int K, int NO, int relu)
{
    __shared__ unsigned short A[64][72];
    int tid = threadIdx.x;
    int lane = tid & 63;
    int w = tid >> 6;
    int m0 = blockIdx.y * 64;
    int nb = blockIdx.x * 64;
    int l15 = lane & 15;
    int lq  = lane >> 4;
    int n = nb + w * 16 + l15;
    int sm = tid >> 3, skq = tid & 7;
    f32x4 acc[4] = {};

    // prologue: stage k-chunk 0
    {
        s16x8 a0 = *(const s16x8*)&inb[(size_t)(m0 + sm) * K + skq * 8];
        s16x8 a1 = *(const s16x8*)&inb[(size_t)(m0 + sm + 32) * K + skq * 8];
        *(s16x8*)&A[sm][skq * 8] = a0;
        *(s16x8*)&A[sm + 32][skq * 8] = a1;
    }
    __syncthreads();
    s16x8 b0 = *(const s16x8*)&Bp[((size_t)(0 + lq) * NO + n) * 8];
    s16x8 b1 = *(const s16x8*)&Bp[((size_t)(4 + lq) * NO + n) * 8];

    int nk = K >> 6;
    for (int t = 0; t < nk; ++t) {
        s16x8 na0, na1, nb0, nb1;
        bool more = (t + 1 < nk);
        if (more) {
            int koff = (t + 1) * 64;
            na0 = *(const s16x8*)&inb[(size_t)(m0 + sm) * K + koff + skq * 8];
            na1 = *(const s16x8*)&inb[(size_t)(m0 + sm + 32) * K + koff + skq * 8];
            int kg = (t + 1) * 8;
            nb0 = *(const s16x8*)&Bp[((size_t)(kg + lq) * NO + n) * 8];
            nb1 = *(const s16x8*)&Bp[((size_t)(kg + 4 + lq) * NO + n) * 8];
        }
        #pragma unroll
        for (int s = 0; s < 4; ++s) {
            s16x8 af = *(const s16x8*)&A[s * 16 + l15][lq * 8];
            acc[s] = __builtin_amdgcn_mfma_f32_16x16x32_bf16(af, b0, acc[s], 0, 0, 0);
        }
        #pragma unroll
        for (int s = 0; s < 4; ++s) {
            s16x8 af = *(const s16x8*)&A[s * 16 + l15][32 + lq * 8];
            acc[s] = __builtin_amdgcn_mfma_f32_16x16x32_bf16(af, b1, acc[s], 0, 0, 0);
        }
        if (more) {
            __syncthreads();
            *(s16x8*)&A[sm][skq * 8] = na0;
            *(s16x8*)&A[sm + 32][skq * 8] = na1;
            __syncthreads();
            b0 = nb0; b1 = nb1;
        }
    }
    float bn = bias[n];
    #pragma unroll
    for (int s = 0; s < 4; ++s) {
        #pragma unroll
        for (int r = 0; r < 4; ++r) {
            int m = m0 + s * 16 + lq * 4 + r;
            float v = acc[s][r] + bn;
            if (relu) v = fmaxf(v, 0.f);
            if (outb) outb[(size_t)m * NO + n] = f2bf(v);
            if (frames && m < 576) {
                int f = m >> 6, b = m & 63;
                frames[(size_t)f * FRAME_ELEMS + b * 128 + n] = v;
            }
        }
    }
}

// ==================== host ====================

extern "C" void kernel_launch(void* const* d_in, const int* in_sizes, int n_in,
                              void* d_out, int out_size, void* d_ws, size_t ws_size,
                              hipStream_t stream) {
    const float* feat   = (const float*)d_in[0];
    const int*   ei_in  = (const int*)d_in[1];
    const float* stats  = (const float*)d_in[4];
    const float* w_gcn  = (const float*)d_in[5];
    const float* b_gcn  = (const float*)d_in[6];
    const float* w_ih   = (const float*)d_in[7];
    const float* w_hh   = (const float*)d_in[8];
    const float* b_ih   = (const float*)d_in[9];
    const float* b_hh   = (const float*)d_in[10];
    const float* wm[6], *bm[6];
    for (int i = 0; i < 6; ++i) { wm[i] = (const float*)d_in[11 + 2*i]; bm[i] = (const float*)d_in[12 + 2*i]; }
    const int mlp_K[6]  = {1024, 2048, 4096, 2048, 1024, 512};
    const int mlp_NO[6] = {2048, 4096, 2048, 1024, 512, 128};

    float* out = (float*)d_out;
    float* ws  = (float*)d_ws;

    // ---------- workspace layout (floats) ----------
    size_t off = 0;
    float* wt_ih = ws + off; off += (size_t)128 * 4096;
    float* wt_hh = ws + off; off += (size_t)1024 * 4096;
    float* wt[6];
    const size_t wt_sz[6] = {(size_t)1024*2048, (size_t)2048*4096, (size_t)4096*2048,
                             (size_t)2048*1024, (size_t)1024*512, (size_t)512*128};
    for (int i = 0; i < 6; ++i) { wt[i] = ws + off; off += wt_sz[i]; }
    float* P      = ws + off; off += (size_t)9 * 4096 * 64;   // 2.36M floats
    float* gT_all = ws + off; off += (size_t)10 * 128 * 64;
    float* gT_dec = ws + off; off += 8192;
    float* hT     = ws + off; off += 65536;
    float* cT     = ws + off; off += 65536;
    float* aT1    = ws + off; off += 131072;
    float* aT2    = ws + off; off += 262144;
    float* aT3    = ws + off; off += 131072;
    float* aT4    = ws + off; off += 65536;
    float* deg    = ws + off; off += (size_t)10 * 4096;
    float* xw     = ws + off; off += (size_t)10 * 8192;
    float* inb1f  = ws + off; off += 327680;                  // 640*1024 bf16
    size_t need_bytes = off * sizeof(float);
    if (ws_size < need_bytes) return;

    // bf16 views: inb2..6 alias P..xw scratch (dead during final MFMA phase)
    unsigned short* inb1 = (unsigned short*)inb1f;
    unsigned short* inb2 = (unsigned short*)P;
    unsigned short* inb3 = inb2 + (size_t)640 * 2048;
    unsigned short* inb4 = inb3 + (size_t)640 * 4096;
    unsigned short* inb5 = inb4 + (size_t)640 * 2048;
    unsigned short* inb6 = inb5 + (size_t)640 * 1024;
    unsigned short* Bp[6];
    {
        unsigned short* base = (unsigned short*)wt[0];
        size_t boff = 0;
        for (int l = 0; l < 6; ++l) { Bp[l] = base + boff; boff += (size_t)mlp_NO[l] * mlp_K[l]; }
    }

    hipMemsetAsync(hT, 0, 2 * 65536 * sizeof(float), stream);
    hipMemsetAsync(inb1, 0, (size_t)640 * 1024 * sizeof(unsigned short), stream);
    hipMemcpyAsync(out, feat, FRAME_ELEMS * sizeof(float), hipMemcpyDeviceToDevice, stream);

    // ---------- upfront: all weight transposes in one launch ----------
    {
        TT8 tasks;
        const float* Wp[8] = {w_ih, w_hh, wm[0], wm[1], wm[2], wm[3], wm[4], wm[5]};
        float* WTp[8] = {wt_ih, wt_hh, wt[0], wt[1], wt[2], wt[3], wt[4], wt[5]};
        int NOs[8] = {4096, 4096, 2048, 4096, 2048, 1024, 512, 128};
        int Ks[8]  = {128, 1024, 1024, 2048, 4096, 2048, 1024, 512};
        int toff = 0;
        for (int j = 0; j < 8; ++j) {
            tasks.t[j] = {Wp[j], WTp[j], NOs[j], Ks[j], toff};
            toff += (Ks[j] >> 5) * (NOs[j] >> 5);
        }
        transpose_all<<<toff, 256, 0, stream>>>(tasks);
    }

    // ---------- upfront: batched GCN for all 10 input frames ----------
    bgcn_init_xw<<<10 * NTOT / 256, 256, 0, stream>>>(feat, w_gcn, deg, xw);
    bgcn_count<<<10 * NEDGE / 256, 256, 0, stream>>>(ei_in, deg);
    bgcn_node<<<10 * NTOT / 256, 256, 0, stream>>>(b_gcn, deg, xw, gT_all);
    bgcn_scatter_lds<<<80, 256, 0, stream>>>(ei_in, deg, xw, gT_all);

    // ---------- 15 serial steps ----------
    for (int s = 0; s < 15; ++s) {
        const float* gT_s = (s <= 9) ? (gT_all + (size_t)s * 8192) : gT_dec;

        // LSTM: ks 0..7 = hh chunks (K=1024, KC=128), ks 8 = ih (K=128)
        gemm_bx4<128><<<dim3(32, 9), 256, 0, stream>>>(hT, gT_s, wt_hh, wt_ih, P, 4096, 8);
        lstm_update2<<<HDIM * BSZ / 256, 256, 0, stream>>>(
            P, b_ih, b_hh, hT, cT, (s <= 8) ? inb1 : nullptr, s * 64);

        if (s >= 9) {
            float* frame = out + (size_t)(s + 1) * FRAME_ELEMS;
            // l1: K=1024 NO=2048 KC=64 SK=16
            gemm_bx4<64><<<dim3(16, 16), 256, 0, stream>>>(hT, nullptr, wt[0], nullptr, P, 2048, 16);
            reduce_relu_kernel<<<2048 * 64 / 256, 256, 0, stream>>>(P, bm[0], aT1, 2048, 16, 1);
            // l2: K=2048 NO=4096 KC=256 SK=8
            gemm_bx4<256><<<dim3(32, 8), 256, 0, stream>>>(aT1, nullptr, wt[1], nullptr, P, 4096, 8);
            reduce_relu_kernel<<<4096 * 64 / 256, 256, 0, stream>>>(P, bm[1], aT2, 4096, 8, 1);
            // l3: K=4096 NO=2048 KC=256 SK=16
            gemm_bx4<256><<<dim3(16, 16), 256, 0, stream>>>(aT2, nullptr, wt[2], nullptr, P, 2048, 16);
            reduce_relu_kernel<<<2048 * 64 / 256, 256, 0, stream>>>(P, bm[2], aT3, 2048, 16, 1);
            // l4: K=2048 NO=1024 KC=64 SK=32
            gemm_bx4<64><<<dim3(8, 32), 256, 0, stream>>>(aT3, nullptr, wt[3], nullptr, P, 1024, 32);
            reduce_relu_kernel<<<1024 * 64 / 256, 256, 0, stream>>>(P, bm[3], aT4, 1024, 32, 1);
            // l5: K=1024 NO=512 KC=64 SK=16 (partials only; finalize3 reduces)
            gemm_bx4<64><<<dim3(4, 16), 256, 0, stream>>>(aT4, nullptr, wt[4], nullptr, P, 512, 16);
            // finalize: reduce l5 + l6 GEMM + frame write (+ adjacency + dense GCN)
            finalize3<<<BSZ, 128, 0, stream>>>(P, bm[4], wt[5], bm[5], stats, w_gcn, b_gcn,
                                               frame, gT_dec, (s < 14) ? 1 : 0);
        }
    }

    // ---------- batched encoder MLP (frames 1..9), bf16 MFMA ----------
    {
        PTasks pt;
        int goff = 0;
        for (int l = 0; l < 6; ++l) {
            pt.W[l] = wm[l]; pt.Bp[l] = Bp[l]; pt.K[l] = mlp_K[l];
            pt.goff[l] = goff;
            goff += mlp_NO[l] * (mlp_K[l] >> 3);
        }
        pt.goff[6] = goff;
        pack_all<<<(goff + 255) / 256, 256, 0, stream>>>(pt);
    }
    unsigned short* chain_in[6]  = {inb1, inb2, inb3, inb4, inb5, inb6};
    unsigned short* chain_out[6] = {inb2, inb3, inb4, inb5, inb6, nullptr};
    for (int l = 0; l < 6; ++l) {
        gemm_mfma2<<<dim3(mlp_NO[l] / 64, 10), 256, 0, stream>>>(
            chain_in[l], Bp[l], bm[l], chain_out[l],
            (l == 5) ? (out + FRAME_ELEMS) : nullptr,
            mlp_K[l], mlp_NO[l], l < 5 ? 1 : 0);
    }
}